// Round 12
// baseline (49.754 us; speedup 1.0000x reference)
//
#include <hip/hip_runtime.h>

#define N 4096
#define M 1024
#define D 64
#define MT 16                             // m-values per thread
#define SPLITS 16                         // N-chunks (champion config)
#define ROWS_PER_BLOCK (N / SPLITS)       // 256
#define ROWS_PER_WAVE  (ROWS_PER_BLOCK/4) // 64
#define NB (ROWS_PER_WAVE / 4)            // 16 four-row batches
#define SITES (M * D)                     // 65536
#define K2_BLOCKS 64
#define PASSES 2   // SLOPE PROBE: K1 min-phase executed twice (idempotent)

// Register-only 3-input min (v_min3_f32), minnum semantics = fminf twice.
__device__ __forceinline__ float min3f(float a, float b, float c) {
    float d;
    asm("v_min3_f32 %0, %1, %2, %3" : "=v"(d) : "v"(a), "v"(b), "v"(c));
    return d;
}

// K1: champion (R9) kernel with the ENTIRE min phase run PASSES times in a
// rolled (#pragma unroll 1) loop. Pass 2 recomputes the same candidate set;
// min is idempotent -> acc and pout are bit-identical to the champion.
// Purpose: measure dDuration/dWork for K1 without changing I-footprint,
// occupancy, VMEM pattern, or any other structure.
__global__ __launch_bounds__(256) void k_minpart(const float* __restrict__ z,
                                                 const float* __restrict__ e,
                                                 const int* __restrict__ idx,
                                                 float* __restrict__ pout,
                                                 float* __restrict__ out,
                                                 int* __restrict__ counter) {
    const int bid = blockIdx.x;
    if (bid == 0 && threadIdx.x == 0) *counter = 0;   // reset for K2, every call

    // fused elementwise outputs: 256 elements per block
    {
        const int i = bid * 256 + (int)threadIdx.x;
        const float zv = z[i];
        const int row = i >> 6, dd = i & 63;
        out[1 + i] = (dd < idx[row]) ? zv : 0.0f;   // z_masked
        out[1 + N * D + i] = zv;                    // z_copy
    }

    const int mt   = bid & 63;    // m-tile
    const int s    = bid >> 6;    // split
    const int lane = threadIdx.x & 63;
    const int w    = threadIdx.x >> 6;
    const int m0   = mt * MT;

    float n2e[MT];
#pragma unroll
    for (int j = 0; j < MT; ++j) n2e[j] = -2.0f * e[(m0 + j) * D + lane];

    float acc[MT];
#pragma unroll
    for (int j = 0; j < MT; ++j) acc[j] = 3.4e38f;

    const float* zp = z + (s * ROWS_PER_BLOCK + w * ROWS_PER_WAVE) * D + lane;

#pragma unroll 1
    for (int pass = 0; pass < PASSES; ++pass) {
        // pipeline prologue: batch 0 loads
        float za = zp[0 * D], zb = zp[1 * D], zc = zp[2 * D], zd = zp[3 * D];
#pragma unroll
        for (int r4 = 0; r4 < NB - 1; ++r4) {   // 15 pipelined batches
            const float na = zp[(4 * r4 + 4) * D];
            const float nb = zp[(4 * r4 + 5) * D];
            const float nc = zp[(4 * r4 + 6) * D];
            const float nd = zp[(4 * r4 + 7) * D];
            const float za2 = za * za, zb2 = zb * zb;
            const float zc2 = zc * zc, zd2 = zd * zd;
#pragma unroll
            for (int j = 0; j < MT; ++j) {
                const float t1 = fmaf(n2e[j], za, za2);
                const float t2 = fmaf(n2e[j], zb, zb2);
                const float t3 = fmaf(n2e[j], zc, zc2);
                const float t4 = fmaf(n2e[j], zd, zd2);
                acc[j] = min3f(acc[j], min3f(t1, t2, t3), t4);
            }
            za = na; zb = nb; zc = nc; zd = nd;
        }
        {   // epilogue: last batch, no prefetch
            const float za2 = za * za, zb2 = zb * zb;
            const float zc2 = zc * zc, zd2 = zd * zd;
#pragma unroll
            for (int j = 0; j < MT; ++j) {
                const float t1 = fmaf(n2e[j], za, za2);
                const float t2 = fmaf(n2e[j], zb, zb2);
                const float t3 = fmaf(n2e[j], zc, zc2);
                const float t4 = fmaf(n2e[j], zd, zd2);
                acc[j] = min3f(acc[j], min3f(t1, t2, t3), t4);
            }
        }
    }

    __shared__ float lds[4][MT * 64];
#pragma unroll
    for (int j = 0; j < MT; ++j) lds[w][j * 64 + lane] = acc[j];
    __syncthreads();
    for (int p = threadIdx.x; p < MT * 64; p += 256) {
        const float v = fminf(fminf(lds[0][p], lds[1][p]),
                              fminf(lds[2][p], lds[3][p]));
        pout[s * SITES + m0 * 64 + p] = v;   // coalesced
    }
}

// K2: champion form, untouched. min over 16 splits + e^2, sum; 64 blocks,
// 4 sites/thread; deterministic last-block finish: 64 PARALLEL coherent reads
// + fixed-order shuffle tree.
__global__ __launch_bounds__(256) void k_minsum(const float* __restrict__ pout,
                                                const float* __restrict__ e,
                                                float* __restrict__ bsums,
                                                int* __restrict__ counter,
                                                float* __restrict__ out) {
    const int t = blockIdx.x * 256 + (int)threadIdx.x;  // 16384 threads
    float local = 0.0f;
#pragma unroll
    for (int k = 0; k < 4; ++k) {
        const int site = t + k * 16384;
        float v = 3.4e38f;
#pragma unroll
        for (int si = 0; si < SPLITS; ++si)
            v = fminf(v, pout[si * SITES + site]);
        const float ev = e[site];
        local += v + ev * ev;
    }
#pragma unroll
    for (int off = 32; off > 0; off >>= 1)
        local += __shfl_down(local, off, 64);
    __shared__ float wsum[4];
    __shared__ int is_last;
    const int lane = threadIdx.x & 63, w = threadIdx.x >> 6;
    if (lane == 0) wsum[w] = local;
    __syncthreads();
    if (threadIdx.x == 0) {
        atomicExch(&bsums[blockIdx.x], (wsum[0] + wsum[1]) + (wsum[2] + wsum[3]));
        __threadfence();
        is_last = (atomicAdd(counter, 1) == K2_BLOCKS - 1);
    }
    __syncthreads();
    if (is_last && threadIdx.x < 64) {
        __threadfence();
        float v = atomicAdd(&bsums[threadIdx.x], 0.0f);  // 64 parallel reads
#pragma unroll
        for (int off = 32; off > 0; off >>= 1)
            v += __shfl_down(v, off, 64);
        if (threadIdx.x == 0) out[0] = v * (1.0f / SITES);
    }
}

extern "C" void kernel_launch(void* const* d_in, const int* in_sizes, int n_in,
                              void* d_out, int out_size, void* d_ws, size_t ws_size,
                              hipStream_t stream) {
    const float* z   = (const float*)d_in[0];
    const float* e   = (const float*)d_in[1];
    const int*   idx = (const int*)d_in[2];
    float* out = (float*)d_out;

    float* pout    = (float*)d_ws;                       // 4 MB partials
    float* bsums   = (float*)d_ws + SPLITS * SITES;      // 64 floats
    int*   counter = (int*)(bsums + K2_BLOCKS);

    k_minpart<<<64 * SPLITS, 256, 0, stream>>>(z, e, idx, pout, out, counter);
    k_minsum<<<K2_BLOCKS, 256, 0, stream>>>(pout, e, bsums, counter, out);
}

// Round 13
// 39.862 us; speedup vs baseline: 1.2482x; 1.2482x over previous
//
#include <hip/hip_runtime.h>

#define N 4096
#define M 1024
#define D 64
#define B 1024
#define NZ (N * D)
#define BIGF 3.4e38f
#define STRIDE_ST 1056
// float-unit offsets into ws
#define OFF_ZS   262144      // sorted columns, 1 MB
#define OFF_ST   524288      // bucket starts (ints), 64*1056
#define OFF_PRM  591872      // per-column {zmin, w, invw, pad}
#define OFF_BS   592128      // 64 block sums
#define OFF_CTR  592200      // arrival counter

// K0: 64 blocks x 256 thr. Transpose z -> zT[d][n] (coalesced both ways via
// LDS tile) + fused z_masked/z_copy outputs + counter reset.
__global__ __launch_bounds__(256) void k_prep(const float* __restrict__ z,
                                              const int* __restrict__ idx,
                                              float* __restrict__ zT,
                                              float* __restrict__ out,
                                              int* __restrict__ ctr) {
    const int b = blockIdx.x, t = (int)threadIdx.x;
    if (b == 0 && t == 0) *ctr = 0;
    __shared__ float tile[64][65];
    __shared__ int sidx[64];
    if (t < 64) sidx[t] = idx[b * 64 + t];
    const int base = b * 64 * 64;
    float vals[16];
#pragma unroll
    for (int k = 0; k < 16; ++k) {
        const int i = t + k * 256;              // coalesced read
        const float v = z[base + i];
        vals[k] = v;
        tile[i >> 6][i & 63] = v;
    }
    __syncthreads();
#pragma unroll
    for (int k = 0; k < 16; ++k) {              // mask + copy (coalesced)
        const int i = t + k * 256;
        const int r = i >> 6, c = i & 63;
        out[1 + base + i] = (c < sidx[r]) ? vals[k] : 0.0f;
        out[1 + NZ + base + i] = vals[k];
    }
#pragma unroll
    for (int k = 0; k < 16; ++k) {              // transpose write (coalesced)
        const int j = t + k * 256;
        const int c = j >> 6, rr = j & 63;
        zT[c * N + b * 64 + rr] = tile[rr][c];
    }
}

// K1: 64 blocks x 1024 thr, one column each: bucket-sort (exact R8 bucket
// math) with shuffle-scan (2 barriers), write sorted col + starts + params.
__global__ __launch_bounds__(1024) void k_sort(const float* __restrict__ zT,
                                               float* __restrict__ zs,
                                               int* __restrict__ stc,
                                               float* __restrict__ prm) {
    const int d = blockIdx.x, t = (int)threadIdx.x;
    const int lane = t & 63, w16 = t >> 6;
    __shared__ float sorted[4096];
    __shared__ int hist[B], ofs[B];
    __shared__ float wred[32];
    __shared__ int wtot[16], wexcl[16];
    __shared__ float s_zmin, s_w, s_invw;

    const float4 v4 = ((const float4*)(zT + d * N))[t];
    float vv[4] = {v4.x, v4.y, v4.z, v4.w};
    float vmin = fminf(fminf(vv[0], vv[1]), fminf(vv[2], vv[3]));
    float vmax = fmaxf(fmaxf(vv[0], vv[1]), fmaxf(vv[2], vv[3]));
#pragma unroll
    for (int off = 32; off > 0; off >>= 1) {
        vmin = fminf(vmin, __shfl_down(vmin, off, 64));
        vmax = fmaxf(vmax, __shfl_down(vmax, off, 64));
    }
    if (lane == 0) { wred[w16] = vmin; wred[16 + w16] = vmax; }
    hist[t] = 0;
    __syncthreads();
    if (t == 0) {
        float mn = wred[0], mx = wred[16];
        for (int i = 1; i < 16; ++i) { mn = fminf(mn, wred[i]); mx = fmaxf(mx, wred[16 + i]); }
        s_zmin = mn;
        s_w = fmaxf((mx - mn) * (1.0f / B), 1e-12f);
        s_invw = 1.0f / s_w;
    }
    __syncthreads();
    const float zmin = s_zmin, invw = s_invw;
    int bk[4];
#pragma unroll
    for (int k = 0; k < 4; ++k) {
        int bb = (int)((vv[k] - zmin) * invw);
        bb = bb < 0 ? 0 : (bb > B - 1 ? B - 1 : bb);
        bk[k] = bb;
        atomicAdd(&hist[bb], 1);
    }
    __syncthreads();
    // exclusive scan of hist: wave shuffle-scan + 16 wave totals (2 barriers)
    const int cnt = hist[t];
    int incl = cnt;
#pragma unroll
    for (int off = 1; off < 64; off <<= 1) {
        const int tmp = __shfl_up(incl, off, 64);
        if (lane >= off) incl += tmp;
    }
    if (lane == 63) wtot[w16] = incl;
    __syncthreads();
    if (t < 16) {
        int v = wtot[t];
#pragma unroll
        for (int off = 1; off < 16; off <<= 1) {
            const int tmp = __shfl_up(v, off, 64);
            if (t >= off) v += tmp;
        }
        wexcl[t] = v - wtot[t];
    }
    __syncthreads();
    const int st = wexcl[w16] + incl - cnt;   // global exclusive start
    ofs[t] = st;
    stc[d * STRIDE_ST + t] = st;
    if (t == 0) {
        stc[d * STRIDE_ST + B] = 4096;
        prm[d * 4] = zmin; prm[d * 4 + 1] = s_w; prm[d * 4 + 2] = s_invw;
    }
    __syncthreads();
#pragma unroll
    for (int k = 0; k < 4; ++k) {
        const int p = atomicAdd(&ofs[bk[k]], 1);
        sorted[p] = vv[k];
    }
    __syncthreads();
    ((float4*)(zs + d * N))[t] = ((const float4*)sorted)[t];
}

// K2: 64 blocks x 1024 thr. Wave handles one column d (uniform params/starts)
// x 64 m-values. R8's proven outward-scan-with-slack (exact). Champion tail.
__global__ __launch_bounds__(1024) void k_query(const float* __restrict__ e,
                                                const float* __restrict__ zs,
                                                const int* __restrict__ stc,
                                                const float* __restrict__ prm,
                                                float* __restrict__ bsums,
                                                int* __restrict__ ctr,
                                                float* __restrict__ out) {
    const int b = blockIdx.x, t = (int)threadIdx.x;
    const int lane = t & 63, w16 = t >> 6;
    const int gw = b * 16 + w16;          // 0..1023
    const int d = gw & 63;
    const int m = ((gw >> 6) << 6) + lane;
    const float q = e[m * D + d];
    const float zmin = prm[d * 4], w = prm[d * 4 + 1], invw = prm[d * 4 + 2];
    const int* st = stc + d * STRIDE_ST;
    const float* zc = zs + d * N;

    int bq = (int)((q - zmin) * invw);
    bq = bq < 0 ? 0 : (bq > B - 1 ? B - 1 : bq);
    float best = BIGF;
    for (int i = st[bq]; i < st[bq + 1]; ++i)
        best = fminf(best, fabsf(zc[i] - q));
    int lo = bq, hi = bq;
    for (;;) {
        const float dL = (lo > 0)     ? (q - fmaf((float)lo, w, zmin))       : BIGF;
        const float dR = (hi < B - 1) ? (fmaf((float)(hi + 1), w, zmin) - q) : BIGF;
        const bool doneL = (best + w <= dL) || (lo == 0);
        const bool doneR = (best + w <= dR) || (hi == B - 1);
        if (doneL && doneR) break;
        if (!doneL) { --lo; for (int i = st[lo]; i < st[lo + 1]; ++i) best = fminf(best, fabsf(zc[i] - q)); }
        if (!doneR) { ++hi; for (int i = st[hi]; i < st[hi + 1]; ++i) best = fminf(best, fabsf(zc[i] - q)); }
    }
    float local = best * best;   // fl(best^2) == reference min (monotone fl)

#pragma unroll
    for (int off = 32; off > 0; off >>= 1)
        local += __shfl_down(local, off, 64);
    __shared__ float wsum[16];
    __shared__ int is_last;
    if (lane == 0) wsum[w16] = local;
    __syncthreads();
    if (t == 0) {
        float sblk = 0.0f;
        for (int i = 0; i < 16; ++i) sblk += wsum[i];
        atomicExch(&bsums[b], sblk);
        __threadfence();
        is_last = (atomicAdd(ctr, 1) == 63);
    }
    __syncthreads();
    if (is_last && t < 64) {
        __threadfence();
        float v = atomicAdd(&bsums[t], 0.0f);   // 64 parallel coherent reads
#pragma unroll
        for (int off = 32; off > 0; off >>= 1)
            v += __shfl_down(v, off, 64);
        if (t == 0) out[0] = v * (1.0f / (M * D));
    }
}

extern "C" void kernel_launch(void* const* d_in, const int* in_sizes, int n_in,
                              void* d_out, int out_size, void* d_ws, size_t ws_size,
                              hipStream_t stream) {
    const float* z   = (const float*)d_in[0];
    const float* e   = (const float*)d_in[1];
    const int*   idx = (const int*)d_in[2];
    float* out  = (float*)d_out;
    float* wsf  = (float*)d_ws;
    float* zT   = wsf;                    // 1 MB
    float* zs   = wsf + OFF_ZS;           // 1 MB sorted
    int*   stc  = (int*)(wsf + OFF_ST);
    float* prm  = wsf + OFF_PRM;
    float* bs   = wsf + OFF_BS;
    int*   ctr  = (int*)(wsf + OFF_CTR);

    k_prep <<<64, 256, 0, stream>>>(z, idx, zT, out, ctr);
    k_sort <<<64, 1024, 0, stream>>>(zT, zs, stc, prm);
    k_query<<<64, 1024, 0, stream>>>(e, zs, stc, prm, bs, ctr, out);
}

// Round 14
// 21.257 us; speedup vs baseline: 2.3406x; 1.8753x over previous
//
#include <hip/hip_runtime.h>

#define N 4096
#define M 1024
#define D 64
#define MT 16                             // m-values per thread
#define SPLITS 16                         // N-chunks (champion config)
#define ROWS_PER_BLOCK (N / SPLITS)       // 256
#define ROWS_PER_WAVE  (ROWS_PER_BLOCK/4) // 64
#define NB (ROWS_PER_WAVE / 4)            // 16 four-row batches
#define SITES (M * D)                     // 65536
#define K2_BLOCKS 64

// Register-only 3-input min (v_min3_f32), minnum semantics = fminf twice.
__device__ __forceinline__ float min3f(float a, float b, float c) {
    float d;
    asm("v_min3_f32 %0, %1, %2, %3" : "=v"(d) : "v"(a), "v"(b), "v"(c));
    return d;
}

// K1: R9 champion, byte-identical. Partial min over an N-chunk for a 16-m
// tile, z_masked/z_copy fused. 1024 blocks, 256 threads, lane = d.
// min_n (z-e)^2 = min_n (z^2-2ez) + e^2, distance-1 software pipeline.
__global__ __launch_bounds__(256) void k_minpart(const float* __restrict__ z,
                                                 const float* __restrict__ e,
                                                 const int* __restrict__ idx,
                                                 float* __restrict__ pout,
                                                 float* __restrict__ out,
                                                 int* __restrict__ counter) {
    const int bid = blockIdx.x;
    if (bid == 0 && threadIdx.x == 0) *counter = 0;   // reset for K2, every call

    // fused elementwise outputs: 256 elements per block
    {
        const int i = bid * 256 + (int)threadIdx.x;
        const float zv = z[i];
        const int row = i >> 6, dd = i & 63;
        out[1 + i] = (dd < idx[row]) ? zv : 0.0f;   // z_masked
        out[1 + N * D + i] = zv;                    // z_copy
    }

    const int mt   = bid & 63;    // m-tile
    const int s    = bid >> 6;    // split
    const int lane = threadIdx.x & 63;
    const int w    = threadIdx.x >> 6;
    const int m0   = mt * MT;

    float n2e[MT];
#pragma unroll
    for (int j = 0; j < MT; ++j) n2e[j] = -2.0f * e[(m0 + j) * D + lane];

    float acc[MT];
#pragma unroll
    for (int j = 0; j < MT; ++j) acc[j] = 3.4e38f;

    const float* zp = z + (s * ROWS_PER_BLOCK + w * ROWS_PER_WAVE) * D + lane;

    // pipeline prologue: batch 0 loads
    float za = zp[0 * D], zb = zp[1 * D], zc = zp[2 * D], zd = zp[3 * D];

#pragma unroll
    for (int r4 = 0; r4 < NB - 1; ++r4) {   // 15 pipelined batches
        const float na = zp[(4 * r4 + 4) * D];
        const float nb = zp[(4 * r4 + 5) * D];
        const float nc = zp[(4 * r4 + 6) * D];
        const float nd = zp[(4 * r4 + 7) * D];
        const float za2 = za * za, zb2 = zb * zb;
        const float zc2 = zc * zc, zd2 = zd * zd;
#pragma unroll
        for (int j = 0; j < MT; ++j) {
            const float t1 = fmaf(n2e[j], za, za2);
            const float t2 = fmaf(n2e[j], zb, zb2);
            const float t3 = fmaf(n2e[j], zc, zc2);
            const float t4 = fmaf(n2e[j], zd, zd2);
            acc[j] = min3f(acc[j], min3f(t1, t2, t3), t4);
        }
        za = na; zb = nb; zc = nc; zd = nd;
    }
    {   // epilogue: last batch, no prefetch
        const float za2 = za * za, zb2 = zb * zb;
        const float zc2 = zc * zc, zd2 = zd * zd;
#pragma unroll
        for (int j = 0; j < MT; ++j) {
            const float t1 = fmaf(n2e[j], za, za2);
            const float t2 = fmaf(n2e[j], zb, zb2);
            const float t3 = fmaf(n2e[j], zc, zc2);
            const float t4 = fmaf(n2e[j], zd, zd2);
            acc[j] = min3f(acc[j], min3f(t1, t2, t3), t4);
        }
    }

    __shared__ float lds[4][MT * 64];
#pragma unroll
    for (int j = 0; j < MT; ++j) lds[w][j * 64 + lane] = acc[j];
    __syncthreads();
    for (int p = threadIdx.x; p < MT * 64; p += 256) {
        const float v = fminf(fminf(lds[0][p], lds[1][p]),
                              fminf(lds[2][p], lds[3][p]));
        pout[s * SITES + m0 * 64 + p] = v;   // coalesced
    }
}

// K2: NEW — vectorized. Each thread owns 4 CONSECUTIVE sites; the 16-split
// min is read as 16 float4 loads (coalesced, independent, 4x fewer VMEM
// issues than the 64-scalar champion form). Per-site min order over splits
// unchanged -> bit-identical site values. Proven 64-parallel-read tail.
__global__ __launch_bounds__(256) void k_minsum(const float* __restrict__ pout,
                                                const float* __restrict__ e,
                                                float* __restrict__ bsums,
                                                int* __restrict__ counter,
                                                float* __restrict__ out) {
    const int t = blockIdx.x * 256 + (int)threadIdx.x;  // 16384 threads
    const int s0 = t * 4;                               // 4 consecutive sites
    float4 v = make_float4(3.4e38f, 3.4e38f, 3.4e38f, 3.4e38f);
#pragma unroll
    for (int si = 0; si < SPLITS; ++si) {
        const float4 p = *(const float4*)(pout + si * SITES + s0);
        v.x = fminf(v.x, p.x); v.y = fminf(v.y, p.y);
        v.z = fminf(v.z, p.z); v.w = fminf(v.w, p.w);
    }
    const float4 ev = *(const float4*)(e + s0);
    float local = ((v.x + ev.x * ev.x) + (v.y + ev.y * ev.y))
                + ((v.z + ev.z * ev.z) + (v.w + ev.w * ev.w));

#pragma unroll
    for (int off = 32; off > 0; off >>= 1)
        local += __shfl_down(local, off, 64);
    __shared__ float wsum[4];
    __shared__ int is_last;
    const int lane = threadIdx.x & 63, w = threadIdx.x >> 6;
    if (lane == 0) wsum[w] = local;
    __syncthreads();
    if (threadIdx.x == 0) {
        atomicExch(&bsums[blockIdx.x], (wsum[0] + wsum[1]) + (wsum[2] + wsum[3]));
        __threadfence();
        is_last = (atomicAdd(counter, 1) == K2_BLOCKS - 1);
    }
    __syncthreads();
    if (is_last && threadIdx.x < 64) {
        __threadfence();
        float v2 = atomicAdd(&bsums[threadIdx.x], 0.0f);  // 64 parallel reads
#pragma unroll
        for (int off = 32; off > 0; off >>= 1)
            v2 += __shfl_down(v2, off, 64);
        if (threadIdx.x == 0) out[0] = v2 * (1.0f / SITES);
    }
}

extern "C" void kernel_launch(void* const* d_in, const int* in_sizes, int n_in,
                              void* d_out, int out_size, void* d_ws, size_t ws_size,
                              hipStream_t stream) {
    const float* z   = (const float*)d_in[0];
    const float* e   = (const float*)d_in[1];
    const int*   idx = (const int*)d_in[2];
    float* out = (float*)d_out;

    float* pout    = (float*)d_ws;                       // 4 MB partials
    float* bsums   = (float*)d_ws + SPLITS * SITES;      // 64 floats
    int*   counter = (int*)(bsums + K2_BLOCKS);

    k_minpart<<<64 * SPLITS, 256, 0, stream>>>(z, e, idx, pout, out, counter);
    k_minsum<<<K2_BLOCKS, 256, 0, stream>>>(pout, e, bsums, counter, out);
}